// Round 12
// baseline (650.070 us; speedup 1.0000x reference)
//
#include <hip/hip_runtime.h>
#include <hip/hip_cooperative_groups.h>
#include <hip/hip_bf16.h>

namespace cg = cooperative_groups;

// OptimizedISM: D [4,256,32,32] f32, S [4,256,64,64] f32 -> Z [4,256,64,64] f32
// Z[b,c,h,w] = sum_{i,j} softmax_j(Q[b,:,h,w]·S[b,:,i,j]/16) * S[b,c,i,j] + Q[b,c,h,w]
// Q = nearest-upsample(D): 1024 distinct queries/batch.
// SINGLE cooperative kernel: cvt -> grid.sync -> qk -> grid.sync -> pv ->
// grid.sync -> red. All phase bodies fit in 34.8 KB LDS (4 blocks/CU).
// Fallback to the proven 4-kernel pipeline if cooperative launch is rejected.

typedef __attribute__((ext_vector_type(8))) short bf16x8;
typedef __attribute__((ext_vector_type(4))) float f32x4;
typedef _Float16 f16;
typedef __attribute__((ext_vector_type(2))) _Float16 f16x2;
typedef __attribute__((ext_vector_type(8))) _Float16 f16x8;

#define MFMA16(a, b, c) __builtin_amdgcn_mfma_f32_16x16x32_bf16(a, b, c, 0, 0, 0)

__device__ __forceinline__ unsigned short f2bf(float v) {
    union { __hip_bfloat16 h; unsigned short u; } cv;
    cv.h = __float2bfloat16(v);
    return cv.u;
}

// async global->LDS, 16B/lane; dest = wave-uniform base + lane*16 (linear).
__device__ __forceinline__ void gl_lds16(const unsigned short* g, unsigned short* l) {
    __builtin_amdgcn_global_load_lds(
        (const __attribute__((address_space(1))) unsigned int*)g,
        (__attribute__((address_space(3))) unsigned int*)l, 16, 0, 0);
}

// Stage a [128 rows][64 cols] bf16 tile into linear LDS [128][64], source
// XOR-swizzled (chunk c8 <- c8^(row&7)) so swizzled ds_read_b128 is
// bank-conflict-free (0 conflicts measured R3-R10). 4 issues/thread.
__device__ __forceinline__ void stage_tile(
    const unsigned short* __restrict__ g, unsigned short* l,
    int gstride, int k0, int wid, int lane)
{
    const int r8 = lane >> 3;
    const int c8 = lane & 7;
    const int scc = c8 ^ r8;
#pragma unroll
    for (int i = 0; i < 4; ++i) {
        const int row = i * 32 + wid * 8 + r8;
        gl_lds16(g + (size_t)row * gstride + k0 + scc * 8, l + row * 64 + c8 * 8);
    }
}

// One BK=64 step of the 64x64 per-wave quadrant: 16 ds_read_b128 + 32 MFMA.
__device__ __forceinline__ void gemm_step(
    const unsigned short* al, const unsigned short* bl,
    f32x4 z[4][4], int lrow, int lgrp)
{
    const int swz = lrow & 7;
#pragma unroll
    for (int kk = 0; kk < 2; ++kk) {
        bf16x8 am[4], bn[4];
        const int ch = ((kk * 4 + lgrp) ^ swz) * 8;
#pragma unroll
        for (int m = 0; m < 4; ++m) am[m] = *(const bf16x8*)&al[(m * 16 + lrow) * 64 + ch];
#pragma unroll
        for (int n = 0; n < 4; ++n) bn[n] = *(const bf16x8*)&bl[(n * 16 + lrow) * 64 + ch];
#pragma unroll
        for (int m = 0; m < 4; ++m)
#pragma unroll
            for (int n = 0; n < 4; ++n) z[m][n] = MFMA16(am[m], bn[n], z[m][n]);
    }
}

// ---------------------------------------------------------------------------
// Phase bodies (shared by mono kernel and fallback pipeline).
// ALL bodies use <= 17408 u16 (34.8 KB) of LDS.
// ---------------------------------------------------------------------------

// cvt job: one 32x32 transpose tile. job<4096: S (->Kt + Vt copy); else D (->Qb).
__device__ void dev_cvt_job(int job,
    const float* __restrict__ S, const float* __restrict__ D,
    unsigned short* __restrict__ Kt, unsigned short* __restrict__ Vt,
    unsigned short* __restrict__ Qb, float* tile, int tid)
{
    const bool isS = job < 4096;
    int ncols, p0, c0, bz;
    const float* in;
    unsigned short* outT;
    unsigned short* outC;
    if (isS) {
        ncols = 4096; in = S; outT = Kt; outC = Vt;
        p0 = (job & 127) << 5; c0 = ((job >> 7) & 7) << 5; bz = job >> 10;
    } else {
        const int j2 = job - 4096;
        ncols = 1024; in = D; outT = Qb; outC = nullptr;
        p0 = (j2 & 31) << 5; c0 = ((j2 >> 5) & 7) << 5; bz = j2 >> 8;
    }
    const int tx = tid & 31;
    const int ty = tid >> 5;

    const float* src = in + ((size_t)bz * 256 + c0) * ncols + p0;
#pragma unroll
    for (int k = 0; k < 4; ++k) {
        const int cc = ty + (k << 3);
        float v = src[(size_t)cc * ncols + tx];
        tile[cc * 33 + tx] = v;
        if (outC) outC[((size_t)bz * 256 + (c0 + cc)) * ncols + p0 + tx] = f2bf(v);
    }
    __syncthreads();
    unsigned short* dst = outT + ((size_t)bz * ncols + p0) * 256 + c0;
#pragma unroll
    for (int k = 0; k < 4; ++k) {
        const int pp = ty + (k << 3);
        dst[(size_t)pp * 256 + tx] = f2bf(tile[tx * 33 + pp]);
    }
    __syncthreads();  // tile reused by next job
}

// qk: one 128q x 128j tile of P = softmax_j(Q K^T / 16). R5-proven config.
__device__ void dev_qk(
    const unsigned short* __restrict__ Kt, const unsigned short* __restrict__ Qb,
    unsigned short* __restrict__ P, unsigned short* smem,
    int b, int qt, int jt, int tid)
{
    unsigned short* alds = smem;            // [128][64]
    unsigned short* blds = smem + 8192;     // [128][64]
    const int wid = tid >> 6;
    const int lane = tid & 63;
    const int lrow = lane & 15;
    const int lgrp = lane >> 4;
    const int wr = wid >> 1;
    const int wc = wid & 1;

    const unsigned short* ag = Qb + ((size_t)b * 1024 + qt * 128) * 256;
    const unsigned short* bg = Kt + ((size_t)b * 4096 + jt * 128) * 256;

    const f32x4 fzero = {0.f, 0.f, 0.f, 0.f};
    f32x4 z[4][4];
#pragma unroll
    for (int m = 0; m < 4; ++m)
#pragma unroll
        for (int n = 0; n < 4; ++n) z[m][n] = fzero;

#pragma unroll 1
    for (int s = 0; s < 4; ++s) {
        stage_tile(ag, alds, 256, s * 64, wid, lane);
        stage_tile(bg, blds, 256, s * 64, wid, lane);
        __syncthreads();
        gemm_step(&alds[wr * 4096], &blds[wc * 4096], z, lrow, lgrp);
        __syncthreads();
    }

    const float SC = 0.09016844f; // log2(e)/16
#pragma unroll
    for (int m = 0; m < 4; ++m) {
        float mr[4], sm[4];
#pragma unroll
        for (int r = 0; r < 4; ++r) {
            float m0 = fmaxf(fmaxf(z[m][0][r], z[m][1][r]), fmaxf(z[m][2][r], z[m][3][r]));
            m0 = fmaxf(m0, __shfl_xor(m0, 1));
            m0 = fmaxf(m0, __shfl_xor(m0, 2));
            m0 = fmaxf(m0, __shfl_xor(m0, 4));
            m0 = fmaxf(m0, __shfl_xor(m0, 8));
            mr[r] = m0;
            sm[r] = 0.f;
        }
#pragma unroll
        for (int n = 0; n < 4; ++n)
#pragma unroll
            for (int r = 0; r < 4; ++r) {
                float p = exp2f((z[m][n][r] - mr[r]) * SC);
                z[m][n][r] = p;
                sm[r] += p;
            }
#pragma unroll
        for (int r = 0; r < 4; ++r) {
            float t = sm[r];
            t += __shfl_xor(t, 1);
            t += __shfl_xor(t, 2);
            t += __shfl_xor(t, 4);
            t += __shfl_xor(t, 8);
            sm[r] = 1.0f / t;
        }
#pragma unroll
        for (int n = 0; n < 4; ++n)
#pragma unroll
            for (int r = 0; r < 4; ++r)
                smem[(wr * 64 + m * 16 + (lgrp << 2) + r) * 136 + wc * 64 + n * 16 + lrow]
                    = f2bf(z[m][n][r] * sm[r]);
    }
    __syncthreads();

    unsigned short* pg = P + ((size_t)b * 1024 + qt * 128) * 4096 + (size_t)jt * 128;
#pragma unroll
    for (int it = 0; it < 8; ++it) {
        const int idx = it * 256 + tid;
        const int qrow = idx >> 4;
        const int k = idx & 15;
        *(bf16x8*)(pg + (size_t)qrow * 4096 + k * 8) = *(const bf16x8*)&smem[qrow * 136 + k * 8];
    }
    __syncthreads();  // smem safe for next phase
}

// pv: one 128q x 128c tile over K-chunk ks (512 wide). SINGLE-buffered
// (A,B = 32 KB total; sbuf-vs-dbuf measured null R5/R9/R10). 8 BK=64 steps.
__device__ void dev_pv(
    const unsigned short* __restrict__ P, const unsigned short* __restrict__ Vt,
    unsigned short* __restrict__ part, unsigned short* smem,
    int b, int qt, int ct, int ks, int tid)
{
    unsigned short* alds = smem;            // [128][64]
    unsigned short* blds = smem + 8192;     // [128][64]
    const int wid = tid >> 6;
    const int lane = tid & 63;
    const int lrow = lane & 15;
    const int lgrp = lane >> 4;
    const int wr = wid >> 1;
    const int wc = wid & 1;

    const unsigned short* ag = P + ((size_t)b * 1024 + qt * 128) * 4096 + (size_t)ks * 512;
    const unsigned short* bg = Vt + ((size_t)b * 256 + ct * 128) * 4096 + (size_t)ks * 512;

    const f32x4 fzero = {0.f, 0.f, 0.f, 0.f};
    f32x4 z[4][4];
#pragma unroll
    for (int m = 0; m < 4; ++m)
#pragma unroll
        for (int n = 0; n < 4; ++n) z[m][n] = fzero;

#pragma unroll 1
    for (int s = 0; s < 8; ++s) {
        stage_tile(ag, alds, 4096, s * 64, wid, lane);
        stage_tile(bg, blds, 4096, s * 64, wid, lane);
        __syncthreads();
        gemm_step(&alds[wr * 4096], &blds[wc * 4096], z, lrow, lgrp);
        __syncthreads();
    }

    // ---- dump f16 tile [128 c][136 q-pad] (4B packed q-pairs), coalesced ----
#pragma unroll
    for (int m = 0; m < 4; ++m)
#pragma unroll
        for (int n = 0; n < 4; ++n) {
            const int c = wc * 64 + n * 16 + lrow;
            const int q = wr * 64 + m * 16 + (lgrp << 2);
            f16x2 h0 = {(f16)z[m][n][0], (f16)z[m][n][1]};
            f16x2 h1 = {(f16)z[m][n][2], (f16)z[m][n][3]};
            *(f16x2*)&smem[c * 136 + q] = h0;
            *(f16x2*)&smem[c * 136 + q + 2] = h1;
        }
    __syncthreads();

    unsigned short* pg = part + (((size_t)ks * 4 + b) * 256 + ct * 128) * 1024 + qt * 128;
#pragma unroll
    for (int it = 0; it < 8; ++it) {
        const int idx = it * 256 + tid;
        const int crow = idx >> 4;
        const int k = idx & 15;
        *(bf16x8*)(pg + (size_t)crow * 1024 + k * 8) = *(const bf16x8*)&smem[crow * 136 + k * 8];
    }
    __syncthreads();
}

// red: Z = sum_ks partial (f16) + D (exact f32), 2x2 upsample duplication.
__device__ void dev_red(
    const unsigned short* __restrict__ part, const float* __restrict__ D,
    float* __restrict__ Z, int blk, int tid)
{
    const int xcd = blk & 7;
    const int b = xcd >> 1;
    const int lin = (blk >> 3) * 256 + tid;  // 0..16383
    const int q8 = lin & 127;
    const int c = ((lin >> 7) & 127) | ((xcd & 1) << 7);
    const int q0 = q8 << 3;

    float v[8];
#pragma unroll
    for (int k = 0; k < 8; ++k) v[k] = 0.f;
#pragma unroll
    for (int ks = 0; ks < 8; ++ks) {
        f16x8 h = *(const f16x8*)&part[(((size_t)ks * 4 + b) * 256 + c) * 1024 + q0];
#pragma unroll
        for (int k = 0; k < 8; ++k) v[k] += (float)h[k];
    }
    const size_t base = ((size_t)b * 256 + c) * 1024 + q0;
#pragma unroll
    for (int k = 0; k < 8; k += 4) {
        f32x4 d = *(const f32x4*)(D + base + k);
#pragma unroll
        for (int t = 0; t < 4; ++t) v[k + t] += d[t];
    }

    const int qh = q0 >> 5, qw = q0 & 31;
    float* o = Z + (((size_t)b * 256 + c) * 64 + qh * 2) * 64 + qw * 2;
#pragma unroll
    for (int k = 0; k < 4; ++k) {
        f32x4 val = {v[k * 2], v[k * 2], v[k * 2 + 1], v[k * 2 + 1]};
        *(f32x4*)(o + k * 4) = val;
        *(f32x4*)(o + 64 + k * 4) = val;
    }
}

// ---------------------------------------------------------------------------
// Mono cooperative kernel: all 4 phases, grid 1024 x 256, 4 blocks/CU.
// ---------------------------------------------------------------------------
__global__ __launch_bounds__(256, 4) void ism_mono(
    const float* __restrict__ S, const float* __restrict__ D,
    unsigned short* __restrict__ Kt, unsigned short* __restrict__ Vt,
    unsigned short* __restrict__ Qb, unsigned short* __restrict__ P,
    unsigned short* __restrict__ part, float* __restrict__ Z)
{
    __shared__ unsigned short smem[17408];  // 34.8 KB — fits ALL phase bodies
    const int tid = threadIdx.x;
    const int blk = blockIdx.x;
    cg::grid_group grid = cg::this_grid();

    // phase 1: cvt (5 jobs/block, 5120 total)
#pragma unroll 1
    for (int i = 0; i < 5; ++i)
        dev_cvt_job(blk * 5 + i, S, D, Kt, Vt, Qb, (float*)smem, tid);
    __threadfence();
    grid.sync();

    // phase 2: qk (1 job/block — exact R5 mapping)
    {
        const int xcd = blk & 7;
        const int b = xcd >> 1;
        const int sub = blk >> 3;
        const int qt = sub & 7;
        const int jt = (sub >> 3) | ((xcd & 1) << 4);
        dev_qk(Kt, Qb, P, smem, b, qt, jt, tid);
    }
    __threadfence();
    grid.sync();

    // phase 3: pv (blocks < 512 active; 2 active blocks/CU as R10)
    if (blk < 512) {
        const int xcd = blk & 7;
        const int b = xcd >> 1;
        const int sub = blk >> 3;
        const int qt = sub & 7;
        const int ct = (sub >> 3) & 1;
        const int ks = ((sub >> 4) & 3) | ((xcd & 1) << 2);
        dev_pv(P, Vt, part, smem, b, qt, ct, ks, tid);
    }
    __threadfence();
    grid.sync();

    // phase 4: red (blocks < 512 active)
    if (blk < 512) dev_red(part, D, Z, blk, tid);
}

// ---------------------------------------------------------------------------
// Fallback pipeline (R10-equivalent) built on the same device functions.
// ---------------------------------------------------------------------------
__global__ __launch_bounds__(256) void k_cvt(
    const float* __restrict__ S, const float* __restrict__ D,
    unsigned short* __restrict__ Kt, unsigned short* __restrict__ Vt,
    unsigned short* __restrict__ Qb)
{
    __shared__ float tile[32 * 33];
#pragma unroll 1
    for (int i = 0; i < 5; ++i)
        dev_cvt_job(blockIdx.x * 5 + i, S, D, Kt, Vt, Qb, tile, threadIdx.x);
}

__global__ __launch_bounds__(256, 4) void k_qk(
    const unsigned short* __restrict__ Kt, const unsigned short* __restrict__ Qb,
    unsigned short* __restrict__ P)
{
    __shared__ unsigned short smem[17408];
    const int blk = blockIdx.x;
    const int xcd = blk & 7;
    const int b = xcd >> 1;
    const int sub = blk >> 3;
    dev_qk(Kt, Qb, P, smem, b, sub & 7, (sub >> 3) | ((xcd & 1) << 4), threadIdx.x);
}

__global__ __launch_bounds__(256, 4) void k_pv(
    const unsigned short* __restrict__ P, const unsigned short* __restrict__ Vt,
    unsigned short* __restrict__ part)
{
    __shared__ unsigned short smem[17408];
    const int blk = blockIdx.x;
    const int xcd = blk & 7;
    const int b = xcd >> 1;
    const int sub = blk >> 3;
    dev_pv(P, Vt, part, smem, b, sub & 7, (sub >> 3) & 1,
           ((sub >> 4) & 3) | ((xcd & 1) << 2), threadIdx.x);
}

__global__ __launch_bounds__(256) void k_red(
    const unsigned short* __restrict__ part, const float* __restrict__ D,
    float* __restrict__ Z)
{
    dev_red(part, D, Z, blockIdx.x, threadIdx.x);
}

// ---------------------------------------------------------------------------
extern "C" void kernel_launch(void* const* d_in, const int* in_sizes, int n_in,
                              void* d_out, int out_size, void* d_ws, size_t ws_size,
                              hipStream_t stream)
{
    const float* D = (const float*)d_in[0];  // [4,256,32,32]
    const float* S = (const float*)d_in[1];  // [4,256,64,64]
    float* Z = (float*)d_out;

    // ws layout (67 MiB used of 256 MiB):
    //  [0,8M)    Kt [4][4096][256] bf16
    //  [8,10M)   Qb [4][1024][256] bf16
    //  [10,42M)  P  [4][1024][4096] bf16
    //  [42,50M)  Vt [4][256][4096] bf16
    //  [50,67M)  part [8][4][256][1024] f16
    char* ws = (char*)d_ws;
    unsigned short* Kt = (unsigned short*)ws;
    unsigned short* Qb = (unsigned short*)(ws + 8388608);
    unsigned short* P  = (unsigned short*)(ws + 10485760);
    unsigned short* Vt = (unsigned short*)(ws + 44040192);
    unsigned short* part = (unsigned short*)(ws + 52428800);

    void* kargs[8] = {(void*)&S, (void*)&D, (void*)&Kt, (void*)&Vt,
                      (void*)&Qb, (void*)&P, (void*)&part, (void*)&Z};
    hipError_t err = hipLaunchCooperativeKernel(
        reinterpret_cast<const void*>(ism_mono), dim3(1024), dim3(256),
        kargs, 0, stream);
    if (err != hipSuccess) {
        (void)hipGetLastError();  // clear error state; fall back to pipeline
        k_cvt<<<1024, 256, 0, stream>>>(S, D, Kt, Vt, Qb);
        k_qk<<<1024, 256, 0, stream>>>(Kt, Qb, P);
        k_pv<<<512, 256, 0, stream>>>(P, Vt, part);
        k_red<<<512, 256, 0, stream>>>(part, D, Z);
    }
}

// Round 13
// 67.568 us; speedup vs baseline: 9.6210x; 9.6210x over previous
//
#include <hip/hip_runtime.h>
#include <hip/hip_bf16.h>

// OptimizedISM: D [4,256,32,32] f32, S [4,256,64,64] f32 -> Z [4,256,64,64] f32
// Z[b,c,h,w] = sum_{i,j} softmax_j(Q[b,:,h,w]·S[b,:,i,j]/16) * S[b,c,i,j] + Q[b,c,h,w]
// Q = nearest-upsample(D): 1024 distinct queries/batch.
// Phase A (NEW): P = softmax(Q K^T): block 64q x 128j, Q IN REGISTERS (64 VGPR),
//   only K staged (16 KB LDS), P-tile aliases stage buffer. Grid 2048.
// Phase B: partial[ks] = P·V (128x128, K-split 4, dbuf — exact R5 proven).
// Reduce: Z = sum_ks partial + D, 2x2 duplicated.

typedef __attribute__((ext_vector_type(8))) short bf16x8;
typedef __attribute__((ext_vector_type(4))) float f32x4;
typedef _Float16 f16;
typedef __attribute__((ext_vector_type(2))) _Float16 f16x2;
typedef __attribute__((ext_vector_type(8))) _Float16 f16x8;

#define MFMA16(a, b, c) __builtin_amdgcn_mfma_f32_16x16x32_bf16(a, b, c, 0, 0, 0)

__device__ __forceinline__ unsigned short f2bf(float v) {
    union { __hip_bfloat16 h; unsigned short u; } cv;
    cv.h = __float2bfloat16(v);
    return cv.u;
}

// async global->LDS, 16B/lane; dest = wave-uniform base + lane*16 (linear).
__device__ __forceinline__ void gl_lds16(const unsigned short* g, unsigned short* l) {
    __builtin_amdgcn_global_load_lds(
        (const __attribute__((address_space(1))) unsigned int*)g,
        (__attribute__((address_space(3))) unsigned int*)l, 16, 0, 0);
}

// Stage a [128 rows][64 cols] bf16 tile into linear LDS [128][64], source
// XOR-swizzled (chunk c8 <- c8^(row&7)) so swizzled ds_read_b128 is
// bank-conflict-free (0 conflicts measured R3-R10). 4 issues/thread.
__device__ __forceinline__ void stage_tile(
    const unsigned short* __restrict__ g, unsigned short* l,
    int gstride, int k0, int wid, int lane)
{
    const int r8 = lane >> 3;
    const int c8 = lane & 7;
    const int scc = c8 ^ r8;
#pragma unroll
    for (int i = 0; i < 4; ++i) {
        const int row = i * 32 + wid * 8 + r8;
        gl_lds16(g + (size_t)row * gstride + k0 + scc * 8, l + row * 64 + c8 * 8);
    }
}

// One BK=64 step of the 64x64 per-wave quadrant: 16 ds_read_b128 + 32 MFMA.
// (used by pv, unchanged from R5)
__device__ __forceinline__ void gemm_step(
    const unsigned short* al, const unsigned short* bl,
    f32x4 z[4][4], int lrow, int lgrp)
{
    const int swz = lrow & 7;
#pragma unroll
    for (int kk = 0; kk < 2; ++kk) {
        bf16x8 am[4], bn[4];
        const int ch = ((kk * 4 + lgrp) ^ swz) * 8;
#pragma unroll
        for (int m = 0; m < 4; ++m) am[m] = *(const bf16x8*)&al[(m * 16 + lrow) * 64 + ch];
#pragma unroll
        for (int n = 0; n < 4; ++n) bn[n] = *(const bf16x8*)&bl[(n * 16 + lrow) * 64 + ch];
#pragma unroll
        for (int m = 0; m < 4; ++m)
#pragma unroll
            for (int n = 0; n < 4; ++n) z[m][n] = MFMA16(am[m], bn[n], z[m][n]);
    }
}

// ---------------------------------------------------------------------------
// Prep (single launch): fp32 [B][256][ncols] -> bf16 transposed [B][ncols][256]
// and optionally same-layout bf16 copy. blockIdx.x < 128: S; else: D.
// ---------------------------------------------------------------------------
__global__ __launch_bounds__(256) void cvt_prep(
    const float* __restrict__ S, const float* __restrict__ D,
    unsigned short* __restrict__ Kt, unsigned short* __restrict__ Vt,
    unsigned short* __restrict__ Qb)
{
    __shared__ float tile[32][33];
    const int bz = blockIdx.z;
    const bool isS = blockIdx.x < 128;
    const int ncols = isS ? 4096 : 1024;
    const float* in = isS ? S : D;
    unsigned short* outT = isS ? Kt : Qb;
    unsigned short* outC = isS ? Vt : nullptr;
    const int p0 = (isS ? blockIdx.x : (blockIdx.x - 128)) << 5;
    const int c0 = blockIdx.y << 5;
    const int tx = threadIdx.x & 31;
    const int ty = threadIdx.x >> 5;

    const float* src = in + ((size_t)bz * 256 + c0) * ncols + p0;
#pragma unroll
    for (int k = 0; k < 4; ++k) {
        const int cc = ty + (k << 3);
        float v = src[(size_t)cc * ncols + tx];
        tile[cc][tx] = v;
        if (outC) outC[((size_t)bz * 256 + (c0 + cc)) * ncols + p0 + tx] = f2bf(v);
    }
    __syncthreads();
    unsigned short* dst = outT + ((size_t)bz * ncols + p0) * 256 + c0;
#pragma unroll
    for (int k = 0; k < 4; ++k) {
        const int pp = ty + (k << 3);
        dst[(size_t)pp * 256 + tx] = f2bf(tile[tx][pp]);
    }
}

// ---------------------------------------------------------------------------
// Phase A: P[b][q][ij] = softmax_j(Q·K^T / 16). Block = 64q x 128j; wave =
// 32q x 64j quadrant (wr = q-half, wc = j-half = one softmax group).
// Q held in registers (aq[2][8], 64 VGPR) for the whole kernel; only K staged
// in LDS (16 KB). P-tile [64][128] aliases the K buffer (exact fit), with
// chunk-XOR swizzle; coalesced 16B/lane copy-out.
// ---------------------------------------------------------------------------
__global__ __launch_bounds__(256, 4) void ism_qk(
    const unsigned short* __restrict__ Kt,  // [4][4096][256] bf16
    const unsigned short* __restrict__ Qb,  // [4][1024][256] bf16
    unsigned short* __restrict__ P)         // [4][1024][4096] bf16
{
    __shared__ unsigned short klds[8192];   // 16 KB: K chunk [128j][64c]; P-tile alias

    const int tid = threadIdx.x;
    const int wid = tid >> 6;
    const int lane = tid & 63;
    const int lrow = lane & 15;
    const int lgrp = lane >> 4;
    const int wr = wid >> 1;  // q-half (32 rows)
    const int wc = wid & 1;   // j-half (64 cols = one softmax group)

    const int blk = blockIdx.x;             // 2048 = 8 xcd * 256
    const int xcd = blk & 7;
    const int b = xcd >> 1;
    const int sub = blk >> 3;               // 0..255
    const int qt = sub & 15;                // 16 q-tiles of 64
    const int jt = (sub >> 4) | ((xcd & 1) << 4);  // 0..31 j-tiles of 128

    // ---- Q fragments in registers: 32 q-rows x 256 c per wave ----
    bf16x8 aq[2][8];
    {
        const unsigned short* qp = Qb
            + ((size_t)b * 1024 + qt * 64 + wr * 32 + lrow) * 256 + lgrp * 8;
#pragma unroll
        for (int m = 0; m < 2; ++m)
#pragma unroll
            for (int kk = 0; kk < 8; ++kk)
                aq[m][kk] = *(const bf16x8*)(qp + (size_t)m * 16 * 256 + kk * 32);
    }

    const unsigned short* bg = Kt + ((size_t)b * 4096 + jt * 128) * 256;

    const f32x4 fzero = {0.f, 0.f, 0.f, 0.f};
    f32x4 z[2][4];
#pragma unroll
    for (int m = 0; m < 2; ++m)
#pragma unroll
        for (int n = 0; n < 4; ++n) z[m][n] = fzero;

    const int swz = lrow & 7;
#pragma unroll
    for (int s = 0; s < 4; ++s) {   // fully unrolled: aq index compile-time
        stage_tile(bg, klds, 256, s * 64, wid, lane);
        __syncthreads();
#pragma unroll
        for (int kk = 0; kk < 2; ++kk) {
            const int ch = ((kk * 4 + lgrp) ^ swz) * 8;
            bf16x8 bn[4];
#pragma unroll
            for (int n = 0; n < 4; ++n)
                bn[n] = *(const bf16x8*)&klds[(wc * 64 + n * 16 + lrow) * 64 + ch];
#pragma unroll
            for (int m = 0; m < 2; ++m)
#pragma unroll
                for (int n = 0; n < 4; ++n)
                    z[m][n] = MFMA16(aq[m][s * 2 + kk], bn[n], z[m][n]);
        }
        __syncthreads();
    }

    // ---- softmax over j (wave's 64-j span = one group) ----
    const float SC = 0.09016844f; // log2(e)/16
#pragma unroll
    for (int m = 0; m < 2; ++m) {
        float mr[4], sm[4];
#pragma unroll
        for (int r = 0; r < 4; ++r) {
            float m0 = fmaxf(fmaxf(z[m][0][r], z[m][1][r]), fmaxf(z[m][2][r], z[m][3][r]));
            m0 = fmaxf(m0, __shfl_xor(m0, 1));
            m0 = fmaxf(m0, __shfl_xor(m0, 2));
            m0 = fmaxf(m0, __shfl_xor(m0, 4));
            m0 = fmaxf(m0, __shfl_xor(m0, 8));
            mr[r] = m0;
            sm[r] = 0.f;
        }
#pragma unroll
        for (int n = 0; n < 4; ++n)
#pragma unroll
            for (int r = 0; r < 4; ++r) {
                float p = exp2f((z[m][n][r] - mr[r]) * SC);
                z[m][n][r] = p;
                sm[r] += p;
            }
#pragma unroll
        for (int r = 0; r < 4; ++r) {
            float t = sm[r];
            t += __shfl_xor(t, 1);
            t += __shfl_xor(t, 2);
            t += __shfl_xor(t, 4);
            t += __shfl_xor(t, 8);
            sm[r] = 1.0f / t;
        }
#pragma unroll
        for (int n = 0; n < 4; ++n)
#pragma unroll
            for (int r = 0; r < 4; ++r) z[m][n][r] *= sm[r];
    }

    // ---- P-tile into aliased LDS [64 rows][128 cols], chunk-XOR swizzle ----
    __syncthreads();  // all waves done reading klds (last gemm)
#pragma unroll
    for (int m = 0; m < 2; ++m)
#pragma unroll
        for (int n = 0; n < 4; ++n)
#pragma unroll
            for (int r = 0; r < 4; ++r) {
                const int row = wr * 32 + m * 16 + (lgrp << 2) + r;
                const int col = wc * 64 + n * 16 + lrow;
                klds[row * 128 + (((col >> 3) ^ (row & 7)) << 3) + (col & 7)]
                    = f2bf(z[m][n][r]);
            }
    __syncthreads();

    // ---- coalesced P write: 4 iters x 16B/lane ----
    unsigned short* pg = P + ((size_t)b * 1024 + qt * 64) * 4096 + (size_t)jt * 128;
#pragma unroll
    for (int it = 0; it < 4; ++it) {
        const int idx = it * 256 + tid;     // 0..1023
        const int row = idx >> 4;           // 0..63
        const int ch = idx & 15;            // 16B chunk in 128-col row
        *(bf16x8*)(pg + (size_t)row * 4096 + ch * 8)
            = *(const bf16x8*)&klds[row * 128 + ((ch ^ (row & 7)) << 3)];
    }
}

// ---------------------------------------------------------------------------
// Phase B (exact R5): partial[ks][b][c][q] = P·V over K-chunk ks (1024 wide).
// Tile 128q x 128c, 16 BK=64 steps, double-buffered. f16 partials.
// ---------------------------------------------------------------------------
__global__ __launch_bounds__(256, 2) void ism_pv(
    const unsigned short* __restrict__ P,    // [4][1024][4096] bf16
    const unsigned short* __restrict__ Vt,   // [4][256][4096] bf16
    unsigned short* __restrict__ part)       // [4ks][4b][256c][1024q] f16
{
    __shared__ unsigned short smem[32768];   // 64 KB: 2x(A,B) stage | f16 tile [128][136]

    const int tid = threadIdx.x;
    const int wid = tid >> 6;
    const int lane = tid & 63;
    const int lrow = lane & 15;
    const int lgrp = lane >> 4;
    const int wr = wid >> 1;
    const int wc = wid & 1;

    const int blk = blockIdx.x;             // 256 = 8 xcd * 32
    const int xcd = blk & 7;
    const int b = xcd >> 1;
    const int sub = blk >> 3;               // 0..31
    const int qt = sub & 7;
    const int ct = (sub >> 3) & 1;
    const int ks = (sub >> 4) | ((xcd & 1) << 1);  // 0..3

    const unsigned short* ag = P + ((size_t)b * 1024 + qt * 128) * 4096 + (size_t)ks * 1024;
    const unsigned short* bg = Vt + ((size_t)b * 256 + ct * 128) * 4096 + (size_t)ks * 1024;

    const f32x4 fzero = {0.f, 0.f, 0.f, 0.f};
    f32x4 z[4][4];
#pragma unroll
    for (int m = 0; m < 4; ++m)
#pragma unroll
        for (int n = 0; n < 4; ++n) z[m][n] = fzero;

    stage_tile(ag, smem, 4096, 0, wid, lane);
    stage_tile(bg, smem + 16384, 4096, 0, wid, lane);
    __syncthreads();

#pragma unroll 1
    for (int s = 0; s < 16; ++s) {
        const int cur = s & 1;
        if (s < 15) {
            stage_tile(ag, smem + (cur ^ 1) * 8192, 4096, (s + 1) * 64, wid, lane);
            stage_tile(bg, smem + 16384 + (cur ^ 1) * 8192, 4096, (s + 1) * 64, wid, lane);
        }
        gemm_step(smem + cur * 8192 + wr * 4096, smem + 16384 + cur * 8192 + wc * 4096,
                  z, lrow, lgrp);
        __syncthreads();
    }

    // ---- dump f16 tile [128 c][136 q-pad] (4B packed q-pairs), coalesced ----
#pragma unroll
    for (int m = 0; m < 4; ++m)
#pragma unroll
        for (int n = 0; n < 4; ++n) {
            const int c = wc * 64 + n * 16 + lrow;
            const int q = wr * 64 + m * 16 + (lgrp << 2);
            f16x2 h0 = {(f16)z[m][n][0], (f16)z[m][n][1]};
            f16x2 h1 = {(f16)z[m][n][2], (f16)z[m][n][3]};
            *(f16x2*)&smem[c * 136 + q] = h0;
            *(f16x2*)&smem[c * 136 + q + 2] = h1;
        }
    __syncthreads();

    unsigned short* pg = part + (((size_t)ks * 4 + b) * 256 + ct * 128) * 1024 + qt * 128;
#pragma unroll
    for (int it = 0; it < 8; ++it) {
        const int idx = it * 256 + tid;
        const int crow = idx >> 4;
        const int k = idx & 15;
        *(bf16x8*)(pg + (size_t)crow * 1024 + k * 8) = *(const bf16x8*)&smem[crow * 136 + k * 8];
    }
}

// ---------------------------------------------------------------------------
// Reduce: Z = sum_ks partial (f16) + D (exact f32), 2x2 upsample duplication.
// ---------------------------------------------------------------------------
__global__ __launch_bounds__(256) void ism_red(
    const unsigned short* __restrict__ part, const float* __restrict__ D,
    float* __restrict__ Z)
{
    const int blk = blockIdx.x;             // 512 = 8 xcd * 64
    const int xcd = blk & 7;
    const int b = xcd >> 1;
    const int lin = (blk >> 3) * 256 + threadIdx.x;  // 0..16383
    const int q8 = lin & 127;               // group of 8 q
    const int c = ((lin >> 7) & 127) | ((xcd & 1) << 7);
    const int q0 = q8 << 3;

    float v[8];
#pragma unroll
    for (int k = 0; k < 8; ++k) v[k] = 0.f;
#pragma unroll
    for (int ks = 0; ks < 4; ++ks) {
        f16x8 h = *(const f16x8*)&part[(((size_t)ks * 4 + b) * 256 + c) * 1024 + q0];
#pragma unroll
        for (int k = 0; k < 8; ++k) v[k] += (float)h[k];
    }
    const size_t base = ((size_t)b * 256 + c) * 1024 + q0;
#pragma unroll
    for (int k = 0; k < 8; k += 4) {
        f32x4 d = *(const f32x4*)(D + base + k);
#pragma unroll
        for (int t = 0; t < 4; ++t) v[k + t] += d[t];
    }

    const int qh = q0 >> 5, qw = q0 & 31;
    float* o = Z + (((size_t)b * 256 + c) * 64 + qh * 2) * 64 + qw * 2;
#pragma unroll
    for (int k = 0; k < 4; ++k) {
        f32x4 val = {v[k * 2], v[k * 2], v[k * 2 + 1], v[k * 2 + 1]};
        *(f32x4*)(o + k * 4) = val;
        *(f32x4*)(o + 64 + k * 4) = val;
    }
}

// ---------------------------------------------------------------------------
extern "C" void kernel_launch(void* const* d_in, const int* in_sizes, int n_in,
                              void* d_out, int out_size, void* d_ws, size_t ws_size,
                              hipStream_t stream)
{
    const float* D = (const float*)d_in[0];  // [4,256,32,32]
    const float* S = (const float*)d_in[1];  // [4,256,64,64]
    float* Z = (float*)d_out;

    // ws layout:
    //  [0,8M)    Kt [4][4096][256] bf16   } dead after ism_qk;
    //  [8,10M)   Qb [4][1024][256] bf16   } part (8.4 MB f16) overlays [0,8.4M)
    //  [10,42M)  P  [4][1024][4096] bf16
    //  [42,50M)  Vt [4][256][4096] bf16
    char* ws = (char*)d_ws;
    unsigned short* Kt = (unsigned short*)ws;
    unsigned short* Qb = (unsigned short*)(ws + 8388608);
    unsigned short* P  = (unsigned short*)(ws + 10485760);
    unsigned short* Vt = (unsigned short*)(ws + 44040192);
    unsigned short* part = (unsigned short*)ws;  // [4][4][256][1024] f16

    cvt_prep<<<dim3(160, 8, 4), 256, 0, stream>>>(S, D, Kt, Vt, Qb);
    ism_qk<<<2048, 256, 0, stream>>>(Kt, Qb, P);
    ism_pv<<<256, 256, 0, stream>>>(P, Vt, part);
    ism_red<<<512, 256, 0, stream>>>(part, D, Z);
}